// Round 7
// baseline (93.280 us; speedup 1.0000x reference)
//
#include <hip/hip_runtime.h>
#include <stdint.h>

#define NN 16384
#define KK 64
#define DD 128
#define PP 8
#define NB 32
#define CH 64
#define MAXCHUNK (NN / CH + NB)   // 288 worst case

typedef unsigned short ushort_t;
typedef __attribute__((ext_vector_type(8))) short short8;
typedef __attribute__((ext_vector_type(4))) float f32x4;

__device__ __forceinline__ ushort_t f2bf(float x) {
    unsigned u = __float_as_uint(x);
    u += 0x7fffu + ((u >> 16) & 1u);     // round-to-nearest-even
    return (ushort_t)(u >> 16);
}
__device__ __forceinline__ float silu_f(float v) { return v / (1.0f + __expf(-v)); }

// ---------------- kA: worklist via stripe-scan + weight bf16 conversion -----
__global__ void kA_prep(const int* __restrict__ batch,
                        const float* __restrict__ W1, const float* __restrict__ W2,
                        const float* __restrict__ W3, const float* __restrict__ W4,
                        ushort_t* __restrict__ Wb, int4* __restrict__ wl,
                        int* __restrict__ nwl, int* __restrict__ starts_g) {
    if (blockIdx.x == 0) {
        __shared__ int bl[NN];          // 64 KB
        __shared__ int starts[NB + 1];
        __shared__ int offs[NB + 1];
        const int t = threadIdx.x;
        // coalesced stage of batch -> LDS
        const int4* b4 = (const int4*)batch;
        int4* l4 = (int4*)bl;
        for (int i = t; i < NN / 4; i += 256) l4[i] = b4[i];
        __syncthreads();
        // stripe-scan: thread t owns rows [t*64, t*64+64)
        {
            int i0 = t * 64;
            int prev = (t == 0) ? -1 : bl[i0 - 1];
            for (int j = 0; j < 64; ++j) {
                int v = bl[i0 + j];
                if (v != prev) {
                    for (int b = prev + 1; b <= v; ++b) starts[b] = i0 + j;
                    prev = v;
                }
            }
            if (t == 255) {
                for (int b = prev + 1; b <= NB; ++b) starts[b] = NN;
            }
        }
        __syncthreads();
        if (t == 0) {
            int off = 0;
            for (int b = 0; b < NB; ++b) {
                offs[b] = off;
                off += (starts[b + 1] - starts[b] + CH - 1) / CH;
            }
            *nwl = off;
        }
        if (t <= NB) starts_g[t] = starts[t];
        __syncthreads();
        if (t < NB) {
            int s = starts[t], e = starts[t + 1], o = offs[t];
            for (int r = s; r < e; r += CH) {
                int4 en; en.x = t; en.y = r; en.z = min(CH, e - r); en.w = 0;
                wl[o++] = en;
            }
        }
    } else {
        int w = blockIdx.x - 1;                 // 0..15
        const float* s = (w >> 2) == 0 ? W1 : (w >> 2) == 1 ? W2 : (w >> 2) == 2 ? W3 : W4;
        int off = (w & 3) * 4096;
        ushort_t* d = Wb + (size_t)(w >> 2) * 16384 + off;
        const float* sp = s + off;
        for (int i = threadIdx.x; i < 4096; i += 256) d[i] = f2bf(sp[i]);
    }
}

// ---------------- kB: pre-MLP + residual + in-register LN + trig + transposes
__global__ __launch_bounds__(256, 4) void kB_pre(
        const float* __restrict__ x, const ushort_t* __restrict__ Wb,
        const float* __restrict__ gamma, const float* __restrict__ beta,
        const float* __restrict__ kdr, const float* __restrict__ damp,
        ushort_t* __restrict__ trig_rm, ushort_t* __restrict__ trigT,
        ushort_t* __restrict__ xresT) {
    __shared__ __align__(16) ushort_t xsb[64][136];   // x bf16, later trig tile
    __shared__ __align__(16) ushort_t t1b[64][136];   // t1, later LN(xres) bf16
    const int t = threadIdx.x, lane = t & 63, wv = t >> 6;
    const int n0 = blockIdx.x * 64;
    const ushort_t* W1b = Wb;
    const ushort_t* W2b = Wb + 16384;

    // phase0: stage x -> bf16
    {
        const float4* src = (const float4*)(x + (size_t)n0 * DD);
        for (int i = t; i < 1024; i += 256) {
            float4 v0 = src[i * 2], v1 = src[i * 2 + 1];
            int r = i >> 4, c = (i & 15) << 3;
            short8 pk;
            pk[0] = (short)f2bf(v0.x); pk[1] = (short)f2bf(v0.y);
            pk[2] = (short)f2bf(v0.z); pk[3] = (short)f2bf(v0.w);
            pk[4] = (short)f2bf(v1.x); pk[5] = (short)f2bf(v1.y);
            pk[6] = (short)f2bf(v1.z); pk[7] = (short)f2bf(v1.w);
            *(short8*)&xsb[r][c] = pk;
        }
    }
    __syncthreads();

    const int ar0 = wv * 16;
    const int fr = (lane >> 4) * 8, cr = lane & 15, rr4 = (lane >> 4) * 4;
    f32x4 acc[8];
    const f32x4 z4 = {0.f, 0.f, 0.f, 0.f};

    // GEMM1: silu(x @ W1^T) -> t1b
#pragma unroll
    for (int nt = 0; nt < 8; ++nt) acc[nt] = z4;
#pragma unroll
    for (int ks = 0; ks < 4; ++ks) {
        short8 af = *(const short8*)&xsb[ar0 + cr][ks * 32 + fr];
#pragma unroll
        for (int nt = 0; nt < 8; ++nt) {
            short8 bf = *(const short8*)&W1b[(size_t)(nt * 16 + cr) * DD + ks * 32 + fr];
            acc[nt] = __builtin_amdgcn_mfma_f32_16x16x32_bf16(af, bf, acc[nt], 0, 0, 0);
        }
    }
#pragma unroll
    for (int nt = 0; nt < 8; ++nt)
#pragma unroll
        for (int r = 0; r < 4; ++r)
            t1b[ar0 + rr4 + r][nt * 16 + cr] = f2bf(silu_f(acc[nt][r]));
    __syncthreads();

    // phase2: GEMM2 (reads t1b) + trig (writes xsb) + residual + in-reg LN
#pragma unroll
    for (int nt = 0; nt < 8; ++nt) acc[nt] = z4;
#pragma unroll
    for (int ks = 0; ks < 4; ++ks) {
        short8 af = *(const short8*)&t1b[ar0 + cr][ks * 32 + fr];
#pragma unroll
        for (int nt = 0; nt < 8; ++nt) {
            short8 bf = *(const short8*)&W2b[(size_t)(nt * 16 + cr) * DD + ks * 32 + fr];
            acc[nt] = __builtin_amdgcn_mfma_f32_16x16x32_bf16(af, bf, acc[nt], 0, 0, 0);
        }
    }
    // trig -> xsb + trig_rm (xsb reads all done at previous barrier)
    for (int i = t; i < 2048; i += 256) {
        int r = i >> 5, kk = (i & 31) * 2;
        float2 kv = *(const float2*)&kdr[(size_t)(n0 + r) * KK + kk];
        float2 dv = *(const float2*)&damp[(size_t)(n0 + r) * KK + kk];
        float s0, c0, s1, c1;
        __sincosf(kv.x, &s0, &c0);
        __sincosf(kv.y, &s1, &c1);
        ushort_t rc0 = f2bf(c0 * dv.x), rc1 = f2bf(c1 * dv.y);
        ushort_t is0 = f2bf(s0 * dv.x), is1 = f2bf(s1 * dv.y);
        xsb[r][kk] = rc0; xsb[r][kk + 1] = rc1;
        xsb[r][64 + kk] = is0; xsb[r][64 + kk + 1] = is1;
        ushort2 a; a.x = rc0; a.y = rc1;
        ushort2 b; b.x = is0; b.y = is1;
        *(ushort2*)&trig_rm[(size_t)(n0 + r) * 128 + kk] = a;
        *(ushort2*)&trig_rm[(size_t)(n0 + r) * 128 + 64 + kk] = b;
    }
    // residual (global x, L1-hot) + LN stats in registers
    float g[8], be[8];
#pragma unroll
    for (int nt = 0; nt < 8; ++nt) { g[nt] = gamma[nt * 16 + cr]; be[nt] = beta[nt * 16 + cr]; }
    float mu[4], rs[4];
#pragma unroll
    for (int r = 0; r < 4; ++r) {
        int row = n0 + ar0 + rr4 + r;
        float s = 0.f, sq = 0.f;
#pragma unroll
        for (int nt = 0; nt < 8; ++nt) {
            float v = x[(size_t)row * DD + nt * 16 + cr] + silu_f(acc[nt][r]);
            acc[nt][r] = v;
            s += v; sq += v * v;
        }
#pragma unroll
        for (int off = 1; off < 16; off <<= 1) {
            s += __shfl_xor(s, off);
            sq += __shfl_xor(sq, off);
        }
        float m = s * (1.0f / 128.0f);
        float var = sq * (1.0f / 128.0f) - m * m;
        mu[r] = m; rs[r] = rsqrtf(var + 1e-5f);
    }
    __syncthreads();   // all t1b reads (GEMM2) done before overwrite

    // phase3: LN values -> t1b (bf16 xres)
#pragma unroll
    for (int nt = 0; nt < 8; ++nt)
#pragma unroll
        for (int r = 0; r < 4; ++r)
            t1b[ar0 + rr4 + r][nt * 16 + cr] =
                f2bf((acc[nt][r] - mu[r]) * rs[r] * g[nt] + be[nt]);
    __syncthreads();

    // phase4: transposed writes
    {
        int m = t >> 1, h = (t & 1) * 32;
#pragma unroll
        for (int q = 0; q < 4; ++q) {
            short8 v;
#pragma unroll
            for (int j = 0; j < 8; ++j) v[j] = (short)xsb[h + q * 8 + j][m];
            *(short8*)&trigT[(size_t)m * NN + n0 + h + q * 8] = v;
        }
#pragma unroll
        for (int q = 0; q < 4; ++q) {
            short8 v;
#pragma unroll
            for (int j = 0; j < 8; ++j) v[j] = (short)t1b[h + q * 8 + j][m];
            *(short8*)&xresT[(size_t)m * NN + n0 + h + q * 8] = v;
        }
    }
}

// ---------------- kS: per-segment scatter, no LDS, no barriers --------------
// block (b, g): sf[b, d0..d0+16, :] in registers; direct-global fragments;
// chunks aligned to absolute 64 with register-masked front/back tails.
__global__ __launch_bounds__(256, 4) void kS_scatter(
        const ushort_t* __restrict__ xresT, const ushort_t* __restrict__ trigT,
        const int* __restrict__ starts_g,
        const float* __restrict__ dp, const float* __restrict__ wup,
        ushort_t* __restrict__ SFTb) {
    const int b = blockIdx.x >> 3, g = blockIdx.x & 7, d0 = g * 16;
    const int t = threadIdx.x, lane = t & 63, wv = t >> 6;
    const int start = starts_g[b], end = starts_g[b + 1];

    const int fr = (lane >> 4) * 8, cr = lane & 15, rr4 = (lane >> 4) * 4;
    const f32x4 z4 = {0.f, 0.f, 0.f, 0.f};
    f32x4 acc[2] = {z4, z4};

    const ushort_t* xbase = xresT + (size_t)(d0 + cr) * NN;
    const ushort_t* tb0 = trigT + (size_t)((wv * 2 + 0) * 16 + cr) * NN;
    const ushort_t* tb1 = trigT + (size_t)((wv * 2 + 1) * 16 + cr) * NN;

    for (int r0 = start & ~(CH - 1); r0 < end; r0 += CH) {
        int lo = start - r0; if (lo < 0) lo = 0;
        int hi = end - r0;   if (hi > CH) hi = CH;
        if (lo == 0 && hi == CH) {
#pragma unroll
            for (int ks = 0; ks < 2; ++ks) {
                short8 af = *(const short8*)(xbase + r0 + ks * 32 + fr);
                short8 b0 = *(const short8*)(tb0 + r0 + ks * 32 + fr);
                short8 b1 = *(const short8*)(tb1 + r0 + ks * 32 + fr);
                acc[0] = __builtin_amdgcn_mfma_f32_16x16x32_bf16(af, b0, acc[0], 0, 0, 0);
                acc[1] = __builtin_amdgcn_mfma_f32_16x16x32_bf16(af, b1, acc[1], 0, 0, 0);
            }
        } else {
#pragma unroll
            for (int ks = 0; ks < 2; ++ks) {
                short8 af, b0, b1;
#pragma unroll
                for (int e = 0; e < 8; ++e) {
                    int c = ks * 32 + fr + e;
                    bool ok = (c >= lo) && (c < hi);
                    af[e] = ok ? (short)xbase[r0 + c] : (short)0;
                    b0[e] = ok ? (short)tb0[r0 + c] : (short)0;
                    b1[e] = ok ? (short)tb1[r0 + c] : (short)0;
                }
                acc[0] = __builtin_amdgcn_mfma_f32_16x16x32_bf16(af, b0, acc[0], 0, 0, 0);
                acc[1] = __builtin_amdgcn_mfma_f32_16x16x32_bf16(af, b1, acc[1], 0, 0, 0);
            }
        }
    }

    // epilogue: kfilter(d, m) + bf16 store (plain)
    float4 p0[2], p1[2];
#pragma unroll
    for (int j = 0; j < 2; ++j) {
        int m = (wv * 2 + j) * 16 + cr;
        int k = m & 63;
        p0[j] = *(const float4*)&dp[k * PP];
        p1[j] = *(const float4*)&dp[k * PP + 4];
    }
#pragma unroll
    for (int r = 0; r < 4; ++r) {
        int d = d0 + rr4 + r;
        float4 w0 = *(const float4*)&wup[d * PP];
        float4 w1 = *(const float4*)&wup[d * PP + 4];
#pragma unroll
        for (int j = 0; j < 2; ++j) {
            int m = (wv * 2 + j) * 16 + cr;
            float kf = p0[j].x * w0.x + p0[j].y * w0.y + p0[j].z * w0.z + p0[j].w * w0.w
                     + p1[j].x * w1.x + p1[j].y * w1.y + p1[j].z * w1.z + p1[j].w * w1.w;
            SFTb[((size_t)b * 128 + d) * 128 + m] = f2bf(acc[j][r] * kf);
        }
    }
}

// ---------------- kD: gather (direct-global SFT) + post-MLP + residual ------
__global__ __launch_bounds__(256, 3) void kD_post(
        const float* __restrict__ x, const ushort_t* __restrict__ trig_rm,
        const ushort_t* __restrict__ SFTb, const ushort_t* __restrict__ Wb,
        const int4* __restrict__ wl, const int* __restrict__ nwl,
        float* __restrict__ out) {
    __shared__ __align__(16) ushort_t xs[64][136];    // xg bf16
    __shared__ __align__(16) ushort_t t1[64][136];
    if (blockIdx.x >= *nwl) return;
    int4 e = wl[blockIdx.x];
    const int b = e.x, r0 = e.y, len = e.z;
    const int t = threadIdx.x, lane = t & 63, wv = t >> 6;
    const ushort_t* W3b = Wb + 32768;
    const ushort_t* W4b = Wb + 49152;
    const ushort_t* SFT = SFTb + (size_t)b * 16384;

    const int fr = (lane >> 4) * 8, cr = lane & 15, rr4 = (lane >> 4) * 4;
    const f32x4 z4 = {0.f, 0.f, 0.f, 0.f};
    f32x4 acc[8];

    // gather: msg(n, d) = sum_m trig_rm[n][m] * SFT[d][m]  (both direct global)
    int nrow = r0 + wv * 16 + cr;
    if (nrow >= NN) nrow = NN - 1;
#pragma unroll
    for (int nt = 0; nt < 8; ++nt) acc[nt] = z4;
#pragma unroll
    for (int ks = 0; ks < 4; ++ks) {
        short8 af = *(const short8*)&trig_rm[(size_t)nrow * 128 + ks * 32 + fr];
#pragma unroll
        for (int nt = 0; nt < 8; ++nt) {
            short8 bf = *(const short8*)&SFT[(size_t)(nt * 16 + cr) * 128 + ks * 32 + fr];
            acc[nt] = __builtin_amdgcn_mfma_f32_16x16x32_bf16(af, bf, acc[nt], 0, 0, 0);
        }
    }

    // xg = x + msg: f32 in regs (same thread owns same (row,col) in GEMM2 out)
    float xk[8][4];
#pragma unroll
    for (int nt = 0; nt < 8; ++nt)
#pragma unroll
        for (int r = 0; r < 4; ++r) {
            int rr = wv * 16 + rr4 + r;
            int row = r0 + rr; if (row >= NN) row = NN - 1;
            float xv = x[(size_t)row * DD + nt * 16 + cr] + acc[nt][r];
            xk[nt][r] = xv;
            xs[rr][nt * 16 + cr] = f2bf(xv);
        }
    __syncthreads();

    const int ar0 = wv * 16;
    // GEMM1: silu(xg @ W3^T) -> t1
#pragma unroll
    for (int nt = 0; nt < 8; ++nt) acc[nt] = z4;
#pragma unroll
    for (int ks = 0; ks < 4; ++ks) {
        short8 af = *(const short8*)&xs[ar0 + cr][ks * 32 + fr];
#pragma unroll
        for (int nt = 0; nt < 8; ++nt) {
            short8 bf = *(const short8*)&W3b[(size_t)(nt * 16 + cr) * DD + ks * 32 + fr];
            acc[nt] = __builtin_amdgcn_mfma_f32_16x16x32_bf16(af, bf, acc[nt], 0, 0, 0);
        }
    }
#pragma unroll
    for (int nt = 0; nt < 8; ++nt)
#pragma unroll
        for (int r = 0; r < 4; ++r)
            t1[ar0 + rr4 + r][nt * 16 + cr] = f2bf(silu_f(acc[nt][r]));
    __syncthreads();

    // GEMM2: out = xg + silu(t1 @ W4^T), masked to len
#pragma unroll
    for (int nt = 0; nt < 8; ++nt) acc[nt] = z4;
#pragma unroll
    for (int ks = 0; ks < 4; ++ks) {
        short8 af = *(const short8*)&t1[ar0 + cr][ks * 32 + fr];
#pragma unroll
        for (int nt = 0; nt < 8; ++nt) {
            short8 bf = *(const short8*)&W4b[(size_t)(nt * 16 + cr) * DD + ks * 32 + fr];
            acc[nt] = __builtin_amdgcn_mfma_f32_16x16x32_bf16(af, bf, acc[nt], 0, 0, 0);
        }
    }
#pragma unroll
    for (int nt = 0; nt < 8; ++nt)
#pragma unroll
        for (int r = 0; r < 4; ++r) {
            int rr = wv * 16 + rr4 + r;
            if (rr < len)
                out[(size_t)(r0 + rr) * DD + nt * 16 + cr] = xk[nt][r] + silu_f(acc[nt][r]);
        }
}

extern "C" void kernel_launch(void* const* d_in, const int* in_sizes, int n_in,
                              void* d_out, int out_size, void* d_ws, size_t ws_size,
                              hipStream_t stream) {
    const float* x      = (const float*)d_in[0];
    const float* kdr    = (const float*)d_in[1];
    const float* damp   = (const float*)d_in[2];
    const int*   batch  = (const int*)d_in[3];
    const float* dp     = (const float*)d_in[4];
    const float* W_pre1 = (const float*)d_in[5];
    const float* W_pre2 = (const float*)d_in[6];
    const float* gamma  = (const float*)d_in[7];
    const float* beta   = (const float*)d_in[8];
    const float* W_up   = (const float*)d_in[9];
    const float* W_upd1 = (const float*)d_in[10];
    const float* W_upd2 = (const float*)d_in[11];
    float* out = (float*)d_out;

    char* w = (char*)d_ws;
    ushort_t* Wb      = (ushort_t*)w;                      // 128 KiB
    int4*     wl      = (int4*)(w + 131072);               // 8 KiB
    int*      nwl     = (int*)(w + 131072 + 8192);
    int*      starts_g= (int*)(w + 131072 + 8192 + 64);    // 33 ints
    size_t o = 131072 + 8192 + 512;
    ushort_t* trig_rm = (ushort_t*)(w + o);  o += (size_t)NN * 128 * 2;      // 4 MB
    ushort_t* trigT   = (ushort_t*)(w + o);  o += (size_t)128 * NN * 2;      // 4 MB
    ushort_t* xresT   = (ushort_t*)(w + o);  o += (size_t)128 * NN * 2;      // 4 MB
    ushort_t* SFTb    = (ushort_t*)(w + o);  o += (size_t)NB * 128 * 128 * 2; // 1 MB

    hipLaunchKernelGGL(kA_prep, dim3(17), dim3(256), 0, stream,
                       batch, W_pre1, W_pre2, W_upd1, W_upd2, Wb, wl, nwl, starts_g);
    hipLaunchKernelGGL(kB_pre, dim3(NN / 64), dim3(256), 0, stream,
                       x, Wb, gamma, beta, kdr, damp, trig_rm, trigT, xresT);
    hipLaunchKernelGGL(kS_scatter, dim3(NB * 8), dim3(256), 0, stream,
                       xresT, trigT, starts_g, dp, W_up, SFTb);
    hipLaunchKernelGGL(kD_post, dim3(MAXCHUNK), dim3(256), 0, stream,
                       x, trig_rm, SFTb, Wb, wl, nwl, out);
}

// Round 8
// 85.243 us; speedup vs baseline: 1.0943x; 1.0943x over previous
//
#include <hip/hip_runtime.h>
#include <stdint.h>

#define NN 16384
#define KK 64
#define DD 128
#define PP 8
#define NB 32
#define CH 64
#define MAXCHUNK (NN / CH + NB)   // 288 worst case

typedef unsigned short ushort_t;
typedef __attribute__((ext_vector_type(8))) short short8;
typedef __attribute__((ext_vector_type(4))) float f32x4;

__device__ __forceinline__ ushort_t f2bf(float x) {
    unsigned u = __float_as_uint(x);
    u += 0x7fffu + ((u >> 16) & 1u);     // round-to-nearest-even
    return (ushort_t)(u >> 16);
}
__device__ __forceinline__ float silu_f(float v) { return v / (1.0f + __expf(-v)); }

// ---------------- kA: worklist via stripe-scan + weight bf16 conversion -----
__global__ void kA_prep(const int* __restrict__ batch,
                        const float* __restrict__ W1, const float* __restrict__ W2,
                        const float* __restrict__ W3, const float* __restrict__ W4,
                        ushort_t* __restrict__ Wb, int4* __restrict__ wl,
                        int* __restrict__ nwl, int* __restrict__ starts_g) {
    if (blockIdx.x == 0) {
        __shared__ int bl[NN];          // 64 KB
        __shared__ int starts[NB + 1];
        __shared__ int offs[NB + 1];
        const int t = threadIdx.x;
        const int4* b4 = (const int4*)batch;
        int4* l4 = (int4*)bl;
        for (int i = t; i < NN / 4; i += 256) l4[i] = b4[i];
        __syncthreads();
        {
            int i0 = t * 64;
            int prev = (t == 0) ? -1 : bl[i0 - 1];
            for (int j = 0; j < 64; ++j) {
                int v = bl[i0 + j];
                if (v != prev) {
                    for (int b = prev + 1; b <= v; ++b) starts[b] = i0 + j;
                    prev = v;
                }
            }
            if (t == 255) {
                for (int b = prev + 1; b <= NB; ++b) starts[b] = NN;
            }
        }
        __syncthreads();
        if (t == 0) {
            int off = 0;
            for (int b = 0; b < NB; ++b) {
                offs[b] = off;
                off += (starts[b + 1] - starts[b] + CH - 1) / CH;
            }
            *nwl = off;
        }
        if (t <= NB) starts_g[t] = starts[t];
        __syncthreads();
        if (t < NB) {
            int s = starts[t], e = starts[t + 1], o = offs[t];
            for (int r = s; r < e; r += CH) {
                int4 en; en.x = t; en.y = r; en.z = min(CH, e - r); en.w = 0;
                wl[o++] = en;
            }
        }
    } else {
        int w = blockIdx.x - 1;                 // 0..15
        const float* s = (w >> 2) == 0 ? W1 : (w >> 2) == 1 ? W2 : (w >> 2) == 2 ? W3 : W4;
        int off = (w & 3) * 4096;
        ushort_t* d = Wb + (size_t)(w >> 2) * 16384 + off;
        const float* sp = s + off;
        for (int i = threadIdx.x; i < 4096; i += 256) d[i] = f2bf(sp[i]);
    }
}

// ---------------- kB: pre-MLP + residual + in-register LN + trig + transposes
__global__ __launch_bounds__(256, 4) void kB_pre(
        const float* __restrict__ x, const ushort_t* __restrict__ Wb,
        const float* __restrict__ gamma, const float* __restrict__ beta,
        const float* __restrict__ kdr, const float* __restrict__ damp,
        ushort_t* __restrict__ trig_rm, ushort_t* __restrict__ trigT,
        ushort_t* __restrict__ xresT) {
    __shared__ __align__(16) ushort_t xsb[64][136];   // x bf16, later trig tile
    __shared__ __align__(16) ushort_t t1b[64][136];   // t1, later LN(xres) bf16
    const int t = threadIdx.x, lane = t & 63, wv = t >> 6;
    const int n0 = blockIdx.x * 64;
    const ushort_t* W1b = Wb;
    const ushort_t* W2b = Wb + 16384;

    // phase0: stage x -> bf16
    {
        const float4* src = (const float4*)(x + (size_t)n0 * DD);
        for (int i = t; i < 1024; i += 256) {
            float4 v0 = src[i * 2], v1 = src[i * 2 + 1];
            int r = i >> 4, c = (i & 15) << 3;
            short8 pk;
            pk[0] = (short)f2bf(v0.x); pk[1] = (short)f2bf(v0.y);
            pk[2] = (short)f2bf(v0.z); pk[3] = (short)f2bf(v0.w);
            pk[4] = (short)f2bf(v1.x); pk[5] = (short)f2bf(v1.y);
            pk[6] = (short)f2bf(v1.z); pk[7] = (short)f2bf(v1.w);
            *(short8*)&xsb[r][c] = pk;
        }
    }
    __syncthreads();

    const int ar0 = wv * 16;
    const int fr = (lane >> 4) * 8, cr = lane & 15, rr4 = (lane >> 4) * 4;
    f32x4 acc[8];
    const f32x4 z4 = {0.f, 0.f, 0.f, 0.f};

    // GEMM1: silu(x @ W1^T) -> t1b
#pragma unroll
    for (int nt = 0; nt < 8; ++nt) acc[nt] = z4;
#pragma unroll
    for (int ks = 0; ks < 4; ++ks) {
        short8 af = *(const short8*)&xsb[ar0 + cr][ks * 32 + fr];
#pragma unroll
        for (int nt = 0; nt < 8; ++nt) {
            short8 bf = *(const short8*)&W1b[(size_t)(nt * 16 + cr) * DD + ks * 32 + fr];
            acc[nt] = __builtin_amdgcn_mfma_f32_16x16x32_bf16(af, bf, acc[nt], 0, 0, 0);
        }
    }
#pragma unroll
    for (int nt = 0; nt < 8; ++nt)
#pragma unroll
        for (int r = 0; r < 4; ++r)
            t1b[ar0 + rr4 + r][nt * 16 + cr] = f2bf(silu_f(acc[nt][r]));
    __syncthreads();

    // phase2: GEMM2 (reads t1b) + trig (writes xsb) + residual + in-reg LN
#pragma unroll
    for (int nt = 0; nt < 8; ++nt) acc[nt] = z4;
#pragma unroll
    for (int ks = 0; ks < 4; ++ks) {
        short8 af = *(const short8*)&t1b[ar0 + cr][ks * 32 + fr];
#pragma unroll
        for (int nt = 0; nt < 8; ++nt) {
            short8 bf = *(const short8*)&W2b[(size_t)(nt * 16 + cr) * DD + ks * 32 + fr];
            acc[nt] = __builtin_amdgcn_mfma_f32_16x16x32_bf16(af, bf, acc[nt], 0, 0, 0);
        }
    }
    // trig -> xsb + trig_rm (xsb reads all done at previous barrier)
    for (int i = t; i < 2048; i += 256) {
        int r = i >> 5, kk = (i & 31) * 2;
        float2 kv = *(const float2*)&kdr[(size_t)(n0 + r) * KK + kk];
        float2 dv = *(const float2*)&damp[(size_t)(n0 + r) * KK + kk];
        float s0, c0, s1, c1;
        __sincosf(kv.x, &s0, &c0);
        __sincosf(kv.y, &s1, &c1);
        ushort_t rc0 = f2bf(c0 * dv.x), rc1 = f2bf(c1 * dv.y);
        ushort_t is0 = f2bf(s0 * dv.x), is1 = f2bf(s1 * dv.y);
        xsb[r][kk] = rc0; xsb[r][kk + 1] = rc1;
        xsb[r][64 + kk] = is0; xsb[r][64 + kk + 1] = is1;
        ushort2 a; a.x = rc0; a.y = rc1;
        ushort2 b; b.x = is0; b.y = is1;
        *(ushort2*)&trig_rm[(size_t)(n0 + r) * 128 + kk] = a;
        *(ushort2*)&trig_rm[(size_t)(n0 + r) * 128 + 64 + kk] = b;
    }
    // residual (global x, L1-hot) + LN stats in registers
    float g[8], be[8];
#pragma unroll
    for (int nt = 0; nt < 8; ++nt) { g[nt] = gamma[nt * 16 + cr]; be[nt] = beta[nt * 16 + cr]; }
    float mu[4], rs[4];
#pragma unroll
    for (int r = 0; r < 4; ++r) {
        int row = n0 + ar0 + rr4 + r;
        float s = 0.f, sq = 0.f;
#pragma unroll
        for (int nt = 0; nt < 8; ++nt) {
            float v = x[(size_t)row * DD + nt * 16 + cr] + silu_f(acc[nt][r]);
            acc[nt][r] = v;
            s += v; sq += v * v;
        }
#pragma unroll
        for (int off = 1; off < 16; off <<= 1) {
            s += __shfl_xor(s, off);
            sq += __shfl_xor(sq, off);
        }
        float m = s * (1.0f / 128.0f);
        float var = sq * (1.0f / 128.0f) - m * m;
        mu[r] = m; rs[r] = rsqrtf(var + 1e-5f);
    }
    __syncthreads();   // all t1b reads (GEMM2) done before overwrite

    // phase3: LN values -> t1b (bf16 xres)
#pragma unroll
    for (int nt = 0; nt < 8; ++nt)
#pragma unroll
        for (int r = 0; r < 4; ++r)
            t1b[ar0 + rr4 + r][nt * 16 + cr] =
                f2bf((acc[nt][r] - mu[r]) * rs[r] * g[nt] + be[nt]);
    __syncthreads();

    // phase4: transposed writes
    {
        int m = t >> 1, h = (t & 1) * 32;
#pragma unroll
        for (int q = 0; q < 4; ++q) {
            short8 v;
#pragma unroll
            for (int j = 0; j < 8; ++j) v[j] = (short)xsb[h + q * 8 + j][m];
            *(short8*)&trigT[(size_t)m * NN + n0 + h + q * 8] = v;
        }
#pragma unroll
        for (int q = 0; q < 4; ++q) {
            short8 v;
#pragma unroll
            for (int j = 0; j < 8; ++j) v[j] = (short)t1b[h + q * 8 + j][m];
            *(short8*)&xresT[(size_t)m * NN + n0 + h + q * 8] = v;
        }
    }
}

// ---------------- kS: per-segment scatter (LDS-staged, no atomics) ----------
__global__ __launch_bounds__(256, 4) void kS_scatter(
        const ushort_t* __restrict__ xresT, const ushort_t* __restrict__ trigT,
        const int* __restrict__ starts_g,
        const float* __restrict__ dp, const float* __restrict__ wup,
        ushort_t* __restrict__ SFTb) {
    __shared__ __align__(16) ushort_t xt[16][72];    // 16 d-rows x 64 r
    __shared__ __align__(16) ushort_t tt[128][72];   // 128 m-rows x 64 r
    const int b = blockIdx.x >> 3, g = blockIdx.x & 7, d0 = g * 16;
    const int t = threadIdx.x, lane = t & 63, wv = t >> 6;
    const int start = starts_g[b], end = starts_g[b + 1];

    const int fr = (lane >> 4) * 8, cr = lane & 15, rr4 = (lane >> 4) * 4;
    const f32x4 z4 = {0.f, 0.f, 0.f, 0.f};
    f32x4 acc[2] = {z4, z4};

    for (int r0 = start; r0 < end; r0 += CH) {
        const int len = min(CH, end - r0);
        // stage 144 rows x 64 cols, coalesced (2 half-rows per index)
        for (int i = t; i < 288; i += 256) {
            int row = i >> 1, h = (i & 1) * 32;
            const ushort_t* src;
            ushort_t* dst;
            if (row < 16) { src = xresT + (size_t)(d0 + row) * NN + r0 + h; dst = &xt[row][h]; }
            else          { src = trigT + (size_t)(row - 16) * NN + r0 + h; dst = &tt[row - 16][h]; }
            if (len == CH) {
#pragma unroll
                for (int q = 0; q < 4; ++q) *(short8*)(dst + q * 8) = *(const short8*)(src + q * 8);
            } else {
                for (int j = 0; j < 32; ++j) { int c = h + j; dst[j] = (c < len) ? src[j] : (ushort_t)0; }
            }
        }
        __syncthreads();
#pragma unroll
        for (int ks = 0; ks < 2; ++ks) {
            short8 af = *(const short8*)&xt[cr][ks * 32 + fr];
#pragma unroll
            for (int j = 0; j < 2; ++j) {
                short8 bf = *(const short8*)&tt[(wv * 2 + j) * 16 + cr][ks * 32 + fr];
                acc[j] = __builtin_amdgcn_mfma_f32_16x16x32_bf16(af, bf, acc[j], 0, 0, 0);
            }
        }
        __syncthreads();
    }

    // epilogue: kfilter(d, m) + bf16 store (plain, no atomics)
    float4 p0[2], p1[2];
#pragma unroll
    for (int j = 0; j < 2; ++j) {
        int m = (wv * 2 + j) * 16 + cr;
        int k = m & 63;
        p0[j] = *(const float4*)&dp[k * PP];
        p1[j] = *(const float4*)&dp[k * PP + 4];
    }
#pragma unroll
    for (int r = 0; r < 4; ++r) {
        int d = d0 + rr4 + r;
        float4 w0 = *(const float4*)&wup[d * PP];
        float4 w1 = *(const float4*)&wup[d * PP + 4];
#pragma unroll
        for (int j = 0; j < 2; ++j) {
            int m = (wv * 2 + j) * 16 + cr;
            float kf = p0[j].x * w0.x + p0[j].y * w0.y + p0[j].z * w0.z + p0[j].w * w0.w
                     + p1[j].x * w1.x + p1[j].y * w1.y + p1[j].z * w1.z + p1[j].w * w1.w;
            SFTb[((size_t)b * 128 + d) * 128 + m] = f2bf(acc[j][r] * kf);
        }
    }
}

// ---------------- kD: gather + post-MLP (LDS-staged, t1 aliases sft) --------
#define SFT_E(r, c) smem[(r) * 136 + (c)]
#define XS_E(r, c)  smem[128 * 136 + (r) * 136 + (c)]
#define T1_E(r, c)  smem[(r) * 136 + (c)]
__global__ __launch_bounds__(256, 3) void kD_post(
        const float* __restrict__ x, const ushort_t* __restrict__ trig_rm,
        const ushort_t* __restrict__ SFTb, const ushort_t* __restrict__ Wb,
        const int4* __restrict__ wl, const int* __restrict__ nwl,
        float* __restrict__ out) {
    __shared__ __align__(16) ushort_t smem[192 * 136];  // sft(128)|xs(64); t1 aliases sft
    if (blockIdx.x >= *nwl) return;
    int4 e = wl[blockIdx.x];
    const int b = e.x, r0 = e.y, len = e.z;
    const int t = threadIdx.x, lane = t & 63, wv = t >> 6;
    const ushort_t* W3b = Wb + 32768;
    const ushort_t* W4b = Wb + 49152;

    // stage SFTb (bf16, already filtered) -> LDS, coalesced
    const ushort_t* src = SFTb + (size_t)b * 16384;
    for (int i = t; i < 2048; i += 256) {
        int r = i >> 4, c = (i & 15) * 8;
        *(short8*)&SFT_E(r, c) = *(const short8*)(src + r * 128 + c);
    }
    __syncthreads();

    const int fr = (lane >> 4) * 8, cr = lane & 15, rr4 = (lane >> 4) * 4;
    const f32x4 z4 = {0.f, 0.f, 0.f, 0.f};
    f32x4 acc[8];

    // gather: msg(n, d) = sum_m trig_rm[n][m] * sft[d][m]
    int nrow = r0 + wv * 16 + cr;
    if (nrow >= NN) nrow = NN - 1;
#pragma unroll
    for (int nt = 0; nt < 8; ++nt) acc[nt] = z4;
#pragma unroll
    for (int ks = 0; ks < 4; ++ks) {
        short8 af = *(const short8*)&trig_rm[(size_t)nrow * 128 + ks * 32 + fr];
#pragma unroll
        for (int nt = 0; nt < 8; ++nt) {
            short8 bf = *(const short8*)&SFT_E(nt * 16 + cr, ks * 32 + fr);
            acc[nt] = __builtin_amdgcn_mfma_f32_16x16x32_bf16(af, bf, acc[nt], 0, 0, 0);
        }
    }

    // xg = x + msg: f32 in regs (same thread owns same (row,col) in GEMM2 out)
    float xk[8][4];
#pragma unroll
    for (int nt = 0; nt < 8; ++nt)
#pragma unroll
        for (int r = 0; r < 4; ++r) {
            int rr = wv * 16 + rr4 + r;
            int row = r0 + rr; if (row >= NN) row = NN - 1;
            float xv = x[(size_t)row * DD + nt * 16 + cr] + acc[nt][r];
            xk[nt][r] = xv;
            XS_E(rr, nt * 16 + cr) = f2bf(xv);
        }
    __syncthreads();   // all sft reads done -> t1 may alias sft below

    const int ar0 = wv * 16;
    // GEMM1: silu(xg @ W3^T) -> t1
#pragma unroll
    for (int nt = 0; nt < 8; ++nt) acc[nt] = z4;
#pragma unroll
    for (int ks = 0; ks < 4; ++ks) {
        short8 af = *(const short8*)&XS_E(ar0 + cr, ks * 32 + fr);
#pragma unroll
        for (int nt = 0; nt < 8; ++nt) {
            short8 bf = *(const short8*)&W3b[(size_t)(nt * 16 + cr) * DD + ks * 32 + fr];
            acc[nt] = __builtin_amdgcn_mfma_f32_16x16x32_bf16(af, bf, acc[nt], 0, 0, 0);
        }
    }
#pragma unroll
    for (int nt = 0; nt < 8; ++nt)
#pragma unroll
        for (int r = 0; r < 4; ++r)
            T1_E(ar0 + rr4 + r, nt * 16 + cr) = f2bf(silu_f(acc[nt][r]));
    __syncthreads();

    // GEMM2: out = xg + silu(t1 @ W4^T), masked to len
#pragma unroll
    for (int nt = 0; nt < 8; ++nt) acc[nt] = z4;
#pragma unroll
    for (int ks = 0; ks < 4; ++ks) {
        short8 af = *(const short8*)&T1_E(ar0 + cr, ks * 32 + fr);
#pragma unroll
        for (int nt = 0; nt < 8; ++nt) {
            short8 bf = *(const short8*)&W4b[(size_t)(nt * 16 + cr) * DD + ks * 32 + fr];
            acc[nt] = __builtin_amdgcn_mfma_f32_16x16x32_bf16(af, bf, acc[nt], 0, 0, 0);
        }
    }
#pragma unroll
    for (int nt = 0; nt < 8; ++nt)
#pragma unroll
        for (int r = 0; r < 4; ++r) {
            int rr = wv * 16 + rr4 + r;
            if (rr < len)
                out[(size_t)(r0 + rr) * DD + nt * 16 + cr] = xk[nt][r] + silu_f(acc[nt][r]);
        }
}

extern "C" void kernel_launch(void* const* d_in, const int* in_sizes, int n_in,
                              void* d_out, int out_size, void* d_ws, size_t ws_size,
                              hipStream_t stream) {
    const float* x      = (const float*)d_in[0];
    const float* kdr    = (const float*)d_in[1];
    const float* damp   = (const float*)d_in[2];
    const int*   batch  = (const int*)d_in[3];
    const float* dp     = (const float*)d_in[4];
    const float* W_pre1 = (const float*)d_in[5];
    const float* W_pre2 = (const float*)d_in[6];
    const float* gamma  = (const float*)d_in[7];
    const float* beta   = (const float*)d_in[8];
    const float* W_up   = (const float*)d_in[9];
    const float* W_upd1 = (const float*)d_in[10];
    const float* W_upd2 = (const float*)d_in[11];
    float* out = (float*)d_out;

    char* w = (char*)d_ws;
    ushort_t* Wb      = (ushort_t*)w;                      // 128 KiB
    int4*     wl      = (int4*)(w + 131072);               // 8 KiB
    int*      nwl     = (int*)(w + 131072 + 8192);
    int*      starts_g= (int*)(w + 131072 + 8192 + 64);    // 33 ints
    size_t o = 131072 + 8192 + 512;
    ushort_t* trig_rm = (ushort_t*)(w + o);  o += (size_t)NN * 128 * 2;      // 4 MB
    ushort_t* trigT   = (ushort_t*)(w + o);  o += (size_t)128 * NN * 2;      // 4 MB
    ushort_t* xresT   = (ushort_t*)(w + o);  o += (size_t)128 * NN * 2;      // 4 MB
    ushort_t* SFTb    = (ushort_t*)(w + o);  o += (size_t)NB * 128 * 128 * 2; // 1 MB

    hipLaunchKernelGGL(kA_prep, dim3(17), dim3(256), 0, stream,
                       batch, W_pre1, W_pre2, W_upd1, W_upd2, Wb, wl, nwl, starts_g);
    hipLaunchKernelGGL(kB_pre, dim3(NN / 64), dim3(256), 0, stream,
                       x, Wb, gamma, beta, kdr, damp, trig_rm, trigT, xresT);
    hipLaunchKernelGGL(kS_scatter, dim3(NB * 8), dim3(256), 0, stream,
                       xresT, trigT, starts_g, dp, W_up, SFTb);
    hipLaunchKernelGGL(kD_post, dim3(MAXCHUNK), dim3(256), 0, stream,
                       x, trig_rm, SFTb, Wb, wl, nwl, out);
}

// Round 9
// 85.118 us; speedup vs baseline: 1.0959x; 1.0015x over previous
//
#include <hip/hip_runtime.h>
#include <stdint.h>

#define NN 16384
#define KK 64
#define DD 128
#define PP 8
#define NB 32
#define CH 64
#define MAXCHUNK (NN / CH + NB)   // 288 worst case

typedef unsigned short ushort_t;
typedef __attribute__((ext_vector_type(8))) short short8;
typedef __attribute__((ext_vector_type(4))) float f32x4;

__device__ __forceinline__ ushort_t f2bf(float x) {
    unsigned u = __float_as_uint(x);
    u += 0x7fffu + ((u >> 16) & 1u);     // round-to-nearest-even
    return (ushort_t)(u >> 16);
}
__device__ __forceinline__ float silu_f(float v) { return v / (1.0f + __expf(-v)); }

// ---------------- kA: worklist via stripe-scan + weight bf16 conversion -----
__global__ void kA_prep(const int* __restrict__ batch,
                        const float* __restrict__ W1, const float* __restrict__ W2,
                        const float* __restrict__ W3, const float* __restrict__ W4,
                        ushort_t* __restrict__ Wb, int4* __restrict__ wl,
                        int* __restrict__ nwl, int* __restrict__ starts_g) {
    if (blockIdx.x == 0) {
        __shared__ int bl[NN];          // 64 KB
        __shared__ int starts[NB + 1];
        __shared__ int offs[NB + 1];
        const int t = threadIdx.x;
        const int4* b4 = (const int4*)batch;
        int4* l4 = (int4*)bl;
        for (int i = t; i < NN / 4; i += 256) l4[i] = b4[i];
        __syncthreads();
        {
            int i0 = t * 64;
            int prev = (t == 0) ? -1 : bl[i0 - 1];
            for (int j = 0; j < 64; ++j) {
                int v = bl[i0 + j];
                if (v != prev) {
                    for (int b = prev + 1; b <= v; ++b) starts[b] = i0 + j;
                    prev = v;
                }
            }
            if (t == 255) {
                for (int b = prev + 1; b <= NB; ++b) starts[b] = NN;
            }
        }
        __syncthreads();
        if (t == 0) {
            int off = 0;
            for (int b = 0; b < NB; ++b) {
                offs[b] = off;
                off += (starts[b + 1] - starts[b] + CH - 1) / CH;
            }
            *nwl = off;
        }
        if (t <= NB) starts_g[t] = starts[t];
        __syncthreads();
        if (t < NB) {
            int s = starts[t], e = starts[t + 1], o = offs[t];
            for (int r = s; r < e; r += CH) {
                int4 en; en.x = t; en.y = r; en.z = min(CH, e - r); en.w = 0;
                wl[o++] = en;
            }
        }
    } else {
        int w = blockIdx.x - 1;                 // 0..15
        const float* s = (w >> 2) == 0 ? W1 : (w >> 2) == 1 ? W2 : (w >> 2) == 2 ? W3 : W4;
        int off = (w & 3) * 4096;
        ushort_t* d = Wb + (size_t)(w >> 2) * 16384 + off;
        const float* sp = s + off;
        for (int i = threadIdx.x; i < 4096; i += 256) d[i] = f2bf(sp[i]);
    }
}

// ---------------- kB: pre-MLP + residual + LN + trig + transposes (512 thr) -
__global__ __launch_bounds__(512, 1) void kB_pre(
        const float* __restrict__ x, const ushort_t* __restrict__ Wb,
        const float* __restrict__ gamma, const float* __restrict__ beta,
        const float* __restrict__ kdr, const float* __restrict__ damp,
        ushort_t* __restrict__ trig_rm, ushort_t* __restrict__ trigT,
        ushort_t* __restrict__ xresT) {
    __shared__ __align__(16) ushort_t xsb[64][136];   // x bf16, later trig tile
    __shared__ __align__(16) ushort_t t1b[64][136];   // t1, later LN(xres) bf16
    __shared__ float2 lnp[64][2];                     // LN partials per (row, col-half)
    const int t = threadIdx.x, lane = t & 63, wv = t >> 6;
    const int n0 = blockIdx.x * 64;
    const ushort_t* W1b = Wb;
    const ushort_t* W2b = Wb + 16384;

    // phase0: stage x -> bf16
    {
        const float4* src = (const float4*)(x + (size_t)n0 * DD);
        for (int i = t; i < 1024; i += 512) {
            float4 v0 = src[i * 2], v1 = src[i * 2 + 1];
            int r = i >> 4, c = (i & 15) << 3;
            short8 pk;
            pk[0] = (short)f2bf(v0.x); pk[1] = (short)f2bf(v0.y);
            pk[2] = (short)f2bf(v0.z); pk[3] = (short)f2bf(v0.w);
            pk[4] = (short)f2bf(v1.x); pk[5] = (short)f2bf(v1.y);
            pk[6] = (short)f2bf(v1.z); pk[7] = (short)f2bf(v1.w);
            *(short8*)&xsb[r][c] = pk;
        }
    }
    __syncthreads();

    const int ar0 = (wv & 3) * 16;        // row group
    const int chf = (wv >> 2) * 64;       // column half base
    const int fr = (lane >> 4) * 8, cr = lane & 15, rr4 = (lane >> 4) * 4;
    f32x4 acc[4];
    const f32x4 z4 = {0.f, 0.f, 0.f, 0.f};

    // GEMM1: silu(x @ W1^T) -> t1b
#pragma unroll
    for (int nt = 0; nt < 4; ++nt) acc[nt] = z4;
#pragma unroll
    for (int ks = 0; ks < 4; ++ks) {
        short8 af = *(const short8*)&xsb[ar0 + cr][ks * 32 + fr];
#pragma unroll
        for (int nt = 0; nt < 4; ++nt) {
            short8 bf = *(const short8*)&W1b[(size_t)(chf + nt * 16 + cr) * DD + ks * 32 + fr];
            acc[nt] = __builtin_amdgcn_mfma_f32_16x16x32_bf16(af, bf, acc[nt], 0, 0, 0);
        }
    }
#pragma unroll
    for (int nt = 0; nt < 4; ++nt)
#pragma unroll
        for (int r = 0; r < 4; ++r)
            t1b[ar0 + rr4 + r][chf + nt * 16 + cr] = f2bf(silu_f(acc[nt][r]));
    __syncthreads();

    // phase2: GEMM2 (reads t1b) + trig (writes xsb) + residual + LN partials
#pragma unroll
    for (int nt = 0; nt < 4; ++nt) acc[nt] = z4;
#pragma unroll
    for (int ks = 0; ks < 4; ++ks) {
        short8 af = *(const short8*)&t1b[ar0 + cr][ks * 32 + fr];
#pragma unroll
        for (int nt = 0; nt < 4; ++nt) {
            short8 bf = *(const short8*)&W2b[(size_t)(chf + nt * 16 + cr) * DD + ks * 32 + fr];
            acc[nt] = __builtin_amdgcn_mfma_f32_16x16x32_bf16(af, bf, acc[nt], 0, 0, 0);
        }
    }
    // trig -> xsb + trig_rm (xsb reads all done at previous barrier)
    for (int i = t; i < 2048; i += 512) {
        int r = i >> 5, kk = (i & 31) * 2;
        float2 kv = *(const float2*)&kdr[(size_t)(n0 + r) * KK + kk];
        float2 dv = *(const float2*)&damp[(size_t)(n0 + r) * KK + kk];
        float s0, c0, s1, c1;
        __sincosf(kv.x, &s0, &c0);
        __sincosf(kv.y, &s1, &c1);
        ushort_t rc0 = f2bf(c0 * dv.x), rc1 = f2bf(c1 * dv.y);
        ushort_t is0 = f2bf(s0 * dv.x), is1 = f2bf(s1 * dv.y);
        xsb[r][kk] = rc0; xsb[r][kk + 1] = rc1;
        xsb[r][64 + kk] = is0; xsb[r][64 + kk + 1] = is1;
        ushort2 a; a.x = rc0; a.y = rc1;
        ushort2 b; b.x = is0; b.y = is1;
        *(ushort2*)&trig_rm[(size_t)(n0 + r) * 128 + kk] = a;
        *(ushort2*)&trig_rm[(size_t)(n0 + r) * 128 + 64 + kk] = b;
    }
    // residual (global x) + LN partial sums (this col-half)
    float g[4], be[4];
#pragma unroll
    for (int nt = 0; nt < 4; ++nt) {
        g[nt] = gamma[chf + nt * 16 + cr];
        be[nt] = beta[chf + nt * 16 + cr];
    }
#pragma unroll
    for (int r = 0; r < 4; ++r) {
        int row = n0 + ar0 + rr4 + r;
        float s = 0.f, sq = 0.f;
#pragma unroll
        for (int nt = 0; nt < 4; ++nt) {
            float v = x[(size_t)row * DD + chf + nt * 16 + cr] + silu_f(acc[nt][r]);
            acc[nt][r] = v;
            s += v; sq += v * v;
        }
#pragma unroll
        for (int off = 1; off < 16; off <<= 1) {
            s += __shfl_xor(s, off);
            sq += __shfl_xor(sq, off);
        }
        if (cr == 0) {
            float2 p; p.x = s; p.y = sq;
            lnp[ar0 + rr4 + r][wv >> 2] = p;
        }
    }
    __syncthreads();   // t1b reads done + lnp ready

    // phase3: LN finalize -> t1b (bf16 xres)
#pragma unroll
    for (int r = 0; r < 4; ++r) {
        int row = ar0 + rr4 + r;
        float2 a = lnp[row][0], b = lnp[row][1];
        float s = a.x + b.x, sq = a.y + b.y;
        float mu = s * (1.0f / 128.0f);
        float var = sq * (1.0f / 128.0f) - mu * mu;
        float rs = rsqrtf(var + 1e-5f);
#pragma unroll
        for (int nt = 0; nt < 4; ++nt)
            t1b[row][chf + nt * 16 + cr] = f2bf((acc[nt][r] - mu) * rs * g[nt] + be[nt]);
    }
    __syncthreads();

    // phase4: transposed writes (512 threads)
    {
        int m = t >> 2, h = (t & 3) * 16;
#pragma unroll
        for (int q = 0; q < 2; ++q) {
            short8 v;
#pragma unroll
            for (int j = 0; j < 8; ++j) v[j] = (short)xsb[h + q * 8 + j][m];
            *(short8*)&trigT[(size_t)m * NN + n0 + h + q * 8] = v;
        }
#pragma unroll
        for (int q = 0; q < 2; ++q) {
            short8 v;
#pragma unroll
            for (int j = 0; j < 8; ++j) v[j] = (short)t1b[h + q * 8 + j][m];
            *(short8*)&xresT[(size_t)m * NN + n0 + h + q * 8] = v;
        }
    }
}

// ---------------- kS: per-segment scatter (512 thr, LDS-staged) -------------
__global__ __launch_bounds__(512, 2) void kS_scatter(
        const ushort_t* __restrict__ xresT, const ushort_t* __restrict__ trigT,
        const int* __restrict__ starts_g,
        const float* __restrict__ dp, const float* __restrict__ wup,
        ushort_t* __restrict__ SFTb) {
    __shared__ __align__(16) ushort_t xt[16][72];    // 16 d-rows x 64 r
    __shared__ __align__(16) ushort_t tt[128][72];   // 128 m-rows x 64 r
    const int b = blockIdx.x >> 3, g = blockIdx.x & 7, d0 = g * 16;
    const int t = threadIdx.x, lane = t & 63, wv = t >> 6;   // wv 0..7 = m-chunk
    const int start = starts_g[b], end = starts_g[b + 1];

    const int fr = (lane >> 4) * 8, cr = lane & 15, rr4 = (lane >> 4) * 4;
    const f32x4 z4 = {0.f, 0.f, 0.f, 0.f};
    f32x4 acc = z4;

    for (int r0 = start; r0 < end; r0 += CH) {
        const int len = min(CH, end - r0);
        for (int i = t; i < 288; i += 512) {
            int row = i >> 1, h = (i & 1) * 32;
            const ushort_t* src;
            ushort_t* dst;
            if (row < 16) { src = xresT + (size_t)(d0 + row) * NN + r0 + h; dst = &xt[row][h]; }
            else          { src = trigT + (size_t)(row - 16) * NN + r0 + h; dst = &tt[row - 16][h]; }
            if (len == CH) {
#pragma unroll
                for (int q = 0; q < 4; ++q) *(short8*)(dst + q * 8) = *(const short8*)(src + q * 8);
            } else {
                for (int j = 0; j < 32; ++j) { int c = h + j; dst[j] = (c < len) ? src[j] : (ushort_t)0; }
            }
        }
        __syncthreads();
#pragma unroll
        for (int ks = 0; ks < 2; ++ks) {
            short8 af = *(const short8*)&xt[cr][ks * 32 + fr];
            short8 bf = *(const short8*)&tt[wv * 16 + cr][ks * 32 + fr];
            acc = __builtin_amdgcn_mfma_f32_16x16x32_bf16(af, bf, acc, 0, 0, 0);
        }
        __syncthreads();
    }

    // epilogue: kfilter(d, m) + bf16 store
    const int m = wv * 16 + cr;
    const int k = m & 63;
    float4 p0 = *(const float4*)&dp[k * PP];
    float4 p1 = *(const float4*)&dp[k * PP + 4];
#pragma unroll
    for (int r = 0; r < 4; ++r) {
        int d = d0 + rr4 + r;
        float4 w0 = *(const float4*)&wup[d * PP];
        float4 w1 = *(const float4*)&wup[d * PP + 4];
        float kf = p0.x * w0.x + p0.y * w0.y + p0.z * w0.z + p0.w * w0.w
                 + p1.x * w1.x + p1.y * w1.y + p1.z * w1.z + p1.w * w1.w;
        SFTb[((size_t)b * 128 + d) * 128 + m] = f2bf(acc[r] * kf);
    }
}

// ---------------- kD: gather + post-MLP (512 thr, coalesced I/O) ------------
#define SFT_E(r, c) smem[(r) * 136 + (c)]
#define T1_E(r, c)  smem[(r) * 136 + (c)]
__global__ __launch_bounds__(512, 1) void kD_post(
        const float* __restrict__ x, const ushort_t* __restrict__ trig_rm,
        const ushort_t* __restrict__ SFTb, const ushort_t* __restrict__ Wb,
        const int4* __restrict__ wl, const int* __restrict__ nwl,
        float* __restrict__ out) {
    __shared__ __align__(16) ushort_t smem[128 * 136];  // sft, later t1
    __shared__ __align__(16) ushort_t xs[64][136];      // xg bf16
    __shared__ __align__(16) float xf[64][132];         // x f32, later out f32
    if (blockIdx.x >= *nwl) return;
    int4 e = wl[blockIdx.x];
    const int b = e.x, r0 = e.y, len = e.z;
    const int t = threadIdx.x, lane = t & 63, wv = t >> 6;
    const ushort_t* W3b = Wb + 32768;
    const ushort_t* W4b = Wb + 49152;

    // stage SFTb (coalesced) + x tile f32 (coalesced)
    {
        const ushort_t* src = SFTb + (size_t)b * 16384;
        for (int i = t; i < 2048; i += 512) {
            int r = i >> 4, c = (i & 15) * 8;
            *(short8*)&SFT_E(r, c) = *(const short8*)(src + r * 128 + c);
        }
        for (int i = t; i < 2048; i += 512) {
            int row = i >> 5, c4 = (i & 31) * 4;
            int gr = r0 + row; if (gr >= NN) gr = NN - 1;
            *(float4*)&xf[row][c4] = *(const float4*)(x + (size_t)gr * DD + c4);
        }
    }
    __syncthreads();

    const int ar0 = (wv & 3) * 16;
    const int chf = (wv >> 2) * 64;
    const int fr = (lane >> 4) * 8, cr = lane & 15, rr4 = (lane >> 4) * 4;
    const f32x4 z4 = {0.f, 0.f, 0.f, 0.f};
    f32x4 acc[4];

    // gather: msg(n, d) = sum_m trig_rm[n][m] * sft[d][m]
    int nrow = r0 + ar0 + cr;
    if (nrow >= NN) nrow = NN - 1;
#pragma unroll
    for (int nt = 0; nt < 4; ++nt) acc[nt] = z4;
#pragma unroll
    for (int ks = 0; ks < 4; ++ks) {
        short8 af = *(const short8*)&trig_rm[(size_t)nrow * 128 + ks * 32 + fr];
#pragma unroll
        for (int nt = 0; nt < 4; ++nt) {
            short8 bf = *(const short8*)&SFT_E(chf + nt * 16 + cr, ks * 32 + fr);
            acc[nt] = __builtin_amdgcn_mfma_f32_16x16x32_bf16(af, bf, acc[nt], 0, 0, 0);
        }
    }

    // xg = x + msg: f32 in regs + bf16 to LDS
    float xk[4][4];
#pragma unroll
    for (int nt = 0; nt < 4; ++nt)
#pragma unroll
        for (int r = 0; r < 4; ++r) {
            int rr = ar0 + rr4 + r;
            float xv = xf[rr][chf + nt * 16 + cr] + acc[nt][r];
            xk[nt][r] = xv;
            xs[rr][chf + nt * 16 + cr] = f2bf(xv);
        }
    __syncthreads();   // sft reads + xf reads done

    // GEMM1: silu(xg @ W3^T) -> t1 (aliases sft)
#pragma unroll
    for (int nt = 0; nt < 4; ++nt) acc[nt] = z4;
#pragma unroll
    for (int ks = 0; ks < 4; ++ks) {
        short8 af = *(const short8*)&xs[ar0 + cr][ks * 32 + fr];
#pragma unroll
        for (int nt = 0; nt < 4; ++nt) {
            short8 bf = *(const short8*)&W3b[(size_t)(chf + nt * 16 + cr) * DD + ks * 32 + fr];
            acc[nt] = __builtin_amdgcn_mfma_f32_16x16x32_bf16(af, bf, acc[nt], 0, 0, 0);
        }
    }
#pragma unroll
    for (int nt = 0; nt < 4; ++nt)
#pragma unroll
        for (int r = 0; r < 4; ++r)
            T1_E(ar0 + rr4 + r, chf + nt * 16 + cr) = f2bf(silu_f(acc[nt][r]));
    __syncthreads();

    // GEMM2: result f32 -> xf
#pragma unroll
    for (int nt = 0; nt < 4; ++nt) acc[nt] = z4;
#pragma unroll
    for (int ks = 0; ks < 4; ++ks) {
        short8 af = *(const short8*)&T1_E(ar0 + cr, ks * 32 + fr);
#pragma unroll
        for (int nt = 0; nt < 4; ++nt) {
            short8 bf = *(const short8*)&W4b[(size_t)(chf + nt * 16 + cr) * DD + ks * 32 + fr];
            acc[nt] = __builtin_amdgcn_mfma_f32_16x16x32_bf16(af, bf, acc[nt], 0, 0, 0);
        }
    }
#pragma unroll
    for (int nt = 0; nt < 4; ++nt)
#pragma unroll
        for (int r = 0; r < 4; ++r)
            xf[ar0 + rr4 + r][chf + nt * 16 + cr] = xk[nt][r] + silu_f(acc[nt][r]);
    __syncthreads();

    // coalesced out write
    for (int i = t; i < 2048; i += 512) {
        int row = i >> 5, c4 = (i & 31) * 4;
        if (row < len)
            *(float4*)(out + (size_t)(r0 + row) * DD + c4) = *(const float4*)&xf[row][c4];
    }
}

extern "C" void kernel_launch(void* const* d_in, const int* in_sizes, int n_in,
                              void* d_out, int out_size, void* d_ws, size_t ws_size,
                              hipStream_t stream) {
    const float* x      = (const float*)d_in[0];
    const float* kdr    = (const float*)d_in[1];
    const float* damp   = (const float*)d_in[2];
    const int*   batch  = (const int*)d_in[3];
    const float* dp     = (const float*)d_in[4];
    const float* W_pre1 = (const float*)d_in[5];
    const float* W_pre2 = (const float*)d_in[6];
    const float* gamma  = (const float*)d_in[7];
    const float* beta   = (const float*)d_in[8];
    const float* W_up   = (const float*)d_in[9];
    const float* W_upd1 = (const float*)d_in[10];
    const float* W_upd2 = (const float*)d_in[11];
    float* out = (float*)d_out;

    char* w = (char*)d_ws;
    ushort_t* Wb      = (ushort_t*)w;                      // 128 KiB
    int4*     wl      = (int4*)(w + 131072);               // 8 KiB
    int*      nwl     = (int*)(w + 131072 + 8192);
    int*      starts_g= (int*)(w + 131072 + 8192 + 64);    // 33 ints
    size_t o = 131072 + 8192 + 512;
    ushort_t* trig_rm = (ushort_t*)(w + o);  o += (size_t)NN * 128 * 2;      // 4 MB
    ushort_t* trigT   = (ushort_t*)(w + o);  o += (size_t)128 * NN * 2;      // 4 MB
    ushort_t* xresT   = (ushort_t*)(w + o);  o += (size_t)128 * NN * 2;      // 4 MB
    ushort_t* SFTb    = (ushort_t*)(w + o);  o += (size_t)NB * 128 * 128 * 2; // 1 MB

    hipLaunchKernelGGL(kA_prep, dim3(17), dim3(256), 0, stream,
                       batch, W_pre1, W_pre2, W_upd1, W_upd2, Wb, wl, nwl, starts_g);
    hipLaunchKernelGGL(kB_pre, dim3(NN / 64), dim3(512), 0, stream,
                       x, Wb, gamma, beta, kdr, damp, trig_rm, trigT, xresT);
    hipLaunchKernelGGL(kS_scatter, dim3(NB * 8), dim3(512), 0, stream,
                       xresT, trigT, starts_g, dp, W_up, SFTb);
    hipLaunchKernelGGL(kD_post, dim3(MAXCHUNK), dim3(512), 0, stream,
                       x, trig_rm, SFTb, Wb, wl, nwl, out);
}